// Round 7
// baseline (9113.415 us; speedup 1.0000x reference)
//
#include <hip/hip_runtime.h>

// MDN-RNN persistent kernel for MI355X (gfx950).  R7 = R4 skeleton, legs removed.
// B=128, T=1000, D_IN=35, H=512, OUT=480.
// 8 batch-groups (16 batches) x 32 h-slice WGs = 256 WGs, 1/CU.
// Exchange (R4-proven flag protocol, tightened):
//   - gate wave w stores its 4-batch h-slice (u64-packed, relaxed agent), drains
//     OWN stores (vmcnt(0)), stores flag[g][s][w]=t+1  (per-wave publish: no
//     pre-flag __syncthreads, no sibling-wave jitter on the publish path)
//   - EVERY wave polls all 128 group flags (2/lane + __all ballot, no sleep);
//     on its own detect it immediately bulk-loads its 1/8 of h (4 u64/lane,
//     coalesced relaxed-agent loads) and ds_writes into h_s (no post-detect
//     barrier before loading)
//   - 2 barriers/step total (R4 had 4)
// R4 lesson: relaxed agent atomics only (no wbl2/inv storms). R5/R6 lessons:
// don't amplify MALL traffic; centralized-flag + parallel bulk load beats
// distributed sentinel polls. B-frags reg-resident (R5 component, kept).

#define NGRP   8
#define NSLICE 32
#define GB     16
#define HH     512
#define TT     1000
#define DIN    35
#define OUTC   480
#define ODC    15
#define HWORDS 2048      // u64 words per group h snapshot (16*512/4)

typedef __bf16 bf16x8 __attribute__((ext_vector_type(8)));
typedef float  f32x4  __attribute__((ext_vector_type(4)));
typedef unsigned short u16;
typedef unsigned int   u32;
typedef unsigned long long u64;

__device__ __forceinline__ u16 f2bf(float x) {
    unsigned int u = __float_as_uint(x);
    u += 0x7FFFu + ((u >> 16) & 1u);
    return (u16)(u >> 16);
}
__device__ __forceinline__ float sigf(float x) { return 1.0f / (1.0f + __expf(-x)); }
__device__ __forceinline__ float tanh_fast(float x) {
    float ax = fabsf(x);
    float e = __expf(-2.0f * ax);
    return copysignf((1.0f - e) / (1.0f + e), x);
}

__global__ void __launch_bounds__(512, 1)
mdn_kernel(const float* __restrict__ inp, const float* __restrict__ Wk,
           const float* __restrict__ Wr,  const float* __restrict__ bg,
           const float* __restrict__ Wd,  const float* __restrict__ bd,
           float* __restrict__ out, u32* __restrict__ flags, u64* __restrict__ hbuf)
{
    __shared__ __attribute__((aligned(16))) u16  wr_s[64 * HH];   // dead after preamble
    __shared__ __attribute__((aligned(16))) u16  wk_s[64 * 64];   // dead after preamble
    __shared__ __attribute__((aligned(16))) u16  wd_s[16 * HH];   // dead after preamble
    __shared__ __attribute__((aligned(16))) u16  h_s [GB * HH];
    __shared__ __attribute__((aligned(16))) u16  in_s[GB * 64];
    __shared__ __attribute__((aligned(16))) float gbuf[4 * 16 * 16]; // [q][batch][col]
    __shared__ __attribute__((aligned(16))) float pbuf[4 * 16 * 16]; // [kw][batch][col]

    const int tid  = threadIdx.x;
    const int lane = tid & 63;
    const int wave = tid >> 6;
    const int g    = blockIdx.x & 7;    // batch group (XCD-affine under round-robin)
    const int s    = blockIdx.x >> 3;   // h-slice 0..31
    const int m16  = lane & 15;
    const int kq   = lane >> 4;

    // ---------------- region A: weight staging + LDS zero-init ----------------
    {
        int n = tid & 63;
        int q = n >> 4, jj = n & 15;
        int col = q * HH + s * 16 + jj;
        for (int k = tid >> 6; k < HH; k += 8)
            wr_s[n * HH + (k ^ ((n & 7) << 3))] = f2bf(Wr[(size_t)k * 2048 + col]);
        for (int k = tid >> 6; k < 64; k += 8)
            wk_s[n * 64 + (k ^ ((n & 7) << 3))] = f2bf(k < DIN ? Wk[(size_t)k * 2048 + col] : 0.0f);
    }
    {
        int n = tid & 15;
        for (int k = tid >> 4; k < HH; k += 32)
            wd_s[n * HH + (k ^ ((n & 7) << 3))] =
                f2bf(n < ODC ? Wd[(size_t)k * OUTC + s * ODC + n] : 0.0f);
    }
    for (int i = tid; i < GB * 64; i += 512) in_s[i] = 0;
    for (int i = tid; i < GB * HH / 8; i += 512) ((uint4*)h_s)[i] = uint4{0,0,0,0}; // h_{-1}=0

    __syncthreads();   // order zero-init before x_0 staging across waves (R3 lesson)

    // ---------------- region B: B-frags to registers, state, x_0 ----------------
    bf16x8 bfr[18];
    if (wave < 4) {
        int n = wave * 16 + m16;
        #pragma unroll
        for (int ks = 0; ks < 16; ++ks) {
            int k0 = 32 * ks + 8 * kq;
            bfr[ks] = *(const bf16x8*)(&wr_s[n * HH + (k0 ^ ((n & 7) << 3))]);
        }
        #pragma unroll
        for (int i = 0; i < 2; ++i) {
            int k0 = 32 * i + 8 * kq;
            bfr[16 + i] = *(const bf16x8*)(&wk_s[n * 64 + (k0 ^ ((n & 7) << 3))]);
        }
    } else {
        int w4 = wave - 4;
        #pragma unroll
        for (int kk = 0; kk < 4; ++kk) {
            int k0 = w4 * 128 + 32 * kk + 8 * kq;
            bfr[kk] = *(const bf16x8*)(&wd_s[m16 * HH + (k0 ^ ((m16 & 7) << 3))]);
        }
    }

    float c_reg = 0.0f;
    float bi = 0.f, bff = 0.f, bgg = 0.f, boo = 0.f, bdv = 0.f;
    int br = 0, jj = 0, oo = 0;
    if (tid < 256) {
        br = tid >> 4; jj = tid & 15;
        int scol = s * 16 + jj;
        bi  = bg[0 * HH + scol];
        bff = bg[1 * HH + scol];
        bgg = bg[2 * HH + scol];
        boo = bg[3 * HH + scol];
        // stage x_0
        const float* ip = inp + ((size_t)(g * GB + br) * TT + 0) * DIN;
        #pragma unroll
        for (int i = 0; i < 3; ++i) {
            int d = jj + 16 * i;
            if (d < DIN) in_s[br * 64 + (d ^ ((br & 7) << 3))] = f2bf(ip[d]);
        }
    } else {
        br = (tid - 256) >> 4; oo = (tid - 256) & 15;
        if (oo < ODC) bdv = bd[s * ODC + oo];
    }
    __syncthreads();

    for (int t = 0; t <= TT; ++t) {
        // invariant: h_s = h_{t-1}, in_s = x_t
        // ---- MFMA phase (B from registers, A from LDS) ----
        if (wave < 4) {
            if (t < TT) {
                f32x4 acc0 = {0.f,0.f,0.f,0.f}, acc1 = {0.f,0.f,0.f,0.f};
                {   // xz contribution (K padded 35->64)
                    int k0 = 8 * kq;
                    bf16x8 a = *(const bf16x8*)(&in_s[m16 * 64 + (k0 ^ ((m16 & 7) << 3))]);
                    acc0 = __builtin_amdgcn_mfma_f32_16x16x32_bf16(a, bfr[16], acc0, 0, 0, 0);
                    int k1 = 32 + 8 * kq;
                    bf16x8 a2 = *(const bf16x8*)(&in_s[m16 * 64 + (k1 ^ ((m16 & 7) << 3))]);
                    acc1 = __builtin_amdgcn_mfma_f32_16x16x32_bf16(a2, bfr[17], acc1, 0, 0, 0);
                }
                #pragma unroll
                for (int ks = 0; ks < 16; ks += 2) {   // h @ Wr, 2-way ILP
                    int k0 = 32 * ks + 8 * kq;
                    bf16x8 a = *(const bf16x8*)(&h_s[m16 * HH + (k0 ^ ((m16 & 7) << 3))]);
                    acc0 = __builtin_amdgcn_mfma_f32_16x16x32_bf16(a, bfr[ks], acc0, 0, 0, 0);
                    int k1 = 32 * (ks + 1) + 8 * kq;
                    bf16x8 a2 = *(const bf16x8*)(&h_s[m16 * HH + (k1 ^ ((m16 & 7) << 3))]);
                    acc1 = __builtin_amdgcn_mfma_f32_16x16x32_bf16(a2, bfr[ks + 1], acc1, 0, 0, 0);
                }
                #pragma unroll
                for (int j = 0; j < 4; ++j)
                    gbuf[wave * 256 + (kq * 4 + j) * 16 + m16] = acc0[j] + acc1[j];
            }
        } else {
            if (t > 0) {    // out row t-1, k-split across waves 4..7
                int w4 = wave - 4;
                f32x4 acc0 = {0.f,0.f,0.f,0.f}, acc1 = {0.f,0.f,0.f,0.f};
                #pragma unroll
                for (int kk = 0; kk < 4; kk += 2) {
                    int k0 = w4 * 128 + 32 * kk + 8 * kq;
                    bf16x8 a = *(const bf16x8*)(&h_s[m16 * HH + (k0 ^ ((m16 & 7) << 3))]);
                    acc0 = __builtin_amdgcn_mfma_f32_16x16x32_bf16(a, bfr[kk], acc0, 0, 0, 0);
                    int k1 = w4 * 128 + 32 * (kk + 1) + 8 * kq;
                    bf16x8 a2 = *(const bf16x8*)(&h_s[m16 * HH + (k1 ^ ((m16 & 7) << 3))]);
                    acc1 = __builtin_amdgcn_mfma_f32_16x16x32_bf16(a2, bfr[kk + 1], acc1, 0, 0, 0);
                }
                #pragma unroll
                for (int j = 0; j < 4; ++j)
                    pbuf[w4 * 256 + (kq * 4 + j) * 16 + m16] = acc0[j] + acc1[j];
            }
        }
        __syncthreads();                                   // #1

        // ---- scalar phase ----
        if (tid < 256) {
            if (t < TT) {
                float iv = gbuf[0 * 256 + br * 16 + jj] + bi;
                float fv = gbuf[1 * 256 + br * 16 + jj] + bff;
                float gv = gbuf[2 * 256 + br * 16 + jj] + bgg;
                float ov = gbuf[3 * 256 + br * 16 + jj] + boo;
                c_reg = sigf(fv) * c_reg + sigf(iv) * tanh_fast(gv);
                float h = sigf(ov) * tanh_fast(c_reg);
                // pack 4 neighboring cols into one u64, store relaxed-agent
                u32 hb = (u32)f2bf(h);
                u32 o1 = (u32)__shfl_xor((int)hb, 1);
                u32 lo = hb | (o1 << 16);                  // valid on even jj
                u32 o2 = (u32)__shfl_xor((int)lo, 2);      // jj%4==0 gets (jj+2,jj+3)
                if ((jj & 3) == 0) {
                    u64 w = (u64)lo | ((u64)o2 << 32);
                    u64* dst = hbuf + (size_t)(t & 1) * (NGRP * HWORDS) + g * HWORDS
                                    + br * 128 + s * 4 + (jj >> 2);
                    __hip_atomic_store(dst, w, __ATOMIC_RELAXED, __HIP_MEMORY_SCOPE_AGENT);
                }
            }
        } else {
            if (t > 0) {    // reduce out partials + store f32
                float v = pbuf[0 * 256 + br * 16 + oo] + pbuf[1 * 256 + br * 16 + oo]
                        + pbuf[2 * 256 + br * 16 + oo] + pbuf[3 * 256 + br * 16 + oo] + bdv;
                if (oo < ODC)
                    out[((size_t)(g * GB + br) * TT + (t - 1)) * OUTC + s * ODC + oo] = v;
            }
            // prefetch x_{t+1} (only writes d<35 slots; pad stays 0 -> no race)
            if (t + 1 < TT) {
                const float* ip = inp + ((size_t)(g * GB + br) * TT + (t + 1)) * DIN;
                #pragma unroll
                for (int i = 0; i < 3; ++i) {
                    int d = oo + 16 * i;
                    if (d < DIN) in_s[br * 64 + (d ^ ((br & 7) << 3))] = f2bf(ip[d]);
                }
            }
        }

        if (t < TT) {
            // ---- per-wave publish: drain OWN h stores, then own flag ----
            if (wave < 4) {
                asm volatile("s_waitcnt vmcnt(0)" ::: "memory");   // h at coherence point
                if (lane == 0)
                    __hip_atomic_store(&flags[g * 128 + s * 4 + wave], (u32)(t + 1),
                                       __ATOMIC_RELAXED, __HIP_MEMORY_SCOPE_AGENT);
            }
            // ---- all-wave poll of 128 group flags (2/lane, no sleep) ----
            {
                const u32* fb = flags + g * 128;
                const u32 target = (u32)(t + 1);
                int spins = 0;
                while (true) {
                    u32 a = __hip_atomic_load(fb + lane,      __ATOMIC_RELAXED, __HIP_MEMORY_SCOPE_AGENT);
                    u32 b = __hip_atomic_load(fb + 64 + lane, __ATOMIC_RELAXED, __HIP_MEMORY_SCOPE_AGENT);
                    if (__all(a >= target && b >= target)) break;
                    if (++spins > (1 << 22)) break;        // bounded bail-out: no hangs
                }
            }
            // ---- per-wave bulk load of 1/8 of h_t + ds_write (no barrier first) ----
            {
                const u64* bp = hbuf + (size_t)(t & 1) * (NGRP * HWORDS) + g * HWORDS;
                u64 v[4];
                #pragma unroll
                for (int i = 0; i < 4; ++i) {
                    int w_idx = wave * 256 + i * 64 + lane;
                    v[i] = __hip_atomic_load(bp + w_idx, __ATOMIC_RELAXED,
                                             __HIP_MEMORY_SCOPE_AGENT);
                }
                #pragma unroll
                for (int i = 0; i < 4; ++i) {
                    int w_idx = wave * 256 + i * 64 + lane;
                    int b  = w_idx >> 7;                   // batch row
                    int k  = (w_idx & 127) * 4;            // h col base (4 cols)
                    int sk = k ^ ((b & 7) << 3);           // XOR swizzle (16B blocks)
                    *(u64*)(&h_s[b * HH + sk]) = v[i];
                }
            }
            __syncthreads();                               // #2
        }
    }
}

extern "C" void kernel_launch(void* const* d_in, const int* in_sizes, int n_in,
                              void* d_out, int out_size, void* d_ws, size_t ws_size,
                              hipStream_t stream) {
    const float* inp = (const float*)d_in[0];
    const float* Wk  = (const float*)d_in[1];
    const float* Wr  = (const float*)d_in[2];
    const float* bg  = (const float*)d_in[3];
    const float* Wd  = (const float*)d_in[4];
    const float* bd  = (const float*)d_in[5];
    float* out = (float*)d_out;

    // ws: [0,4096): flags, 8 groups x 128 u32 (monotonic epochs, zeroed per launch)
    //     [4096, 4096+262144): h double buffers, 2 x 8 x 2048 u64
    char* ws = (char*)d_ws;
    u32* flags = (u32*)ws;
    u64* hbuf  = (u64*)(ws + 4096);
    size_t zbytes = 4096 + (size_t)2 * NGRP * HWORDS * sizeof(u64);
    hipMemsetAsync(d_ws, 0, zbytes, stream);

    hipLaunchKernelGGL(mdn_kernel, dim3(NGRP * NSLICE), dim3(512), 0, stream,
                       inp, Wk, Wr, bg, Wd, bd, out, flags, hbuf);
}

// Round 9
// 4558.709 us; speedup vs baseline: 1.9991x; 1.9991x over previous
//
#include <hip/hip_runtime.h>

// MDN-RNN persistent kernel for MI355X (gfx950).  R9: 2-group skewed interleave.
// B=128, T=1000, D_IN=35, H=512, OUT=480.
// 16 groups x 8 batches; WG (p,s) runs groups 2p,2p+1 (half-iteration skew) so
// each group's h-exchange MALL round-trip hides under the other group's phase.
// Exchange = R4's proven protocol per group: relaxed agent atomics only,
// publish: h u64 stores -> per-wave vmcnt(0) (waves 0-1 only) -> barrier ->
// flag; consume: wave0 polls 32 flags -> barrier -> all-wave coalesced bulk
// load -> ds_write. Raw s_barrier + typed waits replace __syncthreads (which
// force-drains ALL VMEM incl. in-flight x loads). x is per-lane registers
// (each gate lane loads its own 11 floats for its MFMA A-fragment, 1 iter
// ahead) -- no LDS staging for x at all.
// Lessons: R8 never trust placement; R7 minimal pollers; R5/R6 no traffic
// amplification; R1/R3 no cache-wide maintenance ops.

#define NGRP   16
#define GB     8
#define HH     512
#define TT     1000
#define DIN    35
#define OUTC   480
#define ODC    15
#define HW     1024     // u64 words per group h snapshot (8*512/4)

typedef __bf16 bf16x8 __attribute__((ext_vector_type(8)));
typedef float  f32x4  __attribute__((ext_vector_type(4)));
typedef unsigned short u16;
typedef unsigned int   u32;
typedef unsigned long long u64;

__device__ __forceinline__ u16 f2bf(float x) {
    u32 u = __float_as_uint(x);
    u += 0x7FFFu + ((u >> 16) & 1u);
    return (u16)(u >> 16);
}
__device__ __forceinline__ u32 pk2(float a, float b) {
    return (u32)f2bf(a) | ((u32)f2bf(b) << 16);
}
__device__ __forceinline__ float sigf(float x) { return 1.0f / (1.0f + __expf(-x)); }
__device__ __forceinline__ float tanh_fast(float x) {
    float ax = fabsf(x);
    float e = __expf(-2.0f * ax);
    return copysignf((1.0f - e) / (1.0f + e), x);
}

union bf8u { u32 u[4]; bf16x8 v; };

// raw barrier with compiler-level memory fence + sched pin (rule #18)
#define BARRIER() do { asm volatile("" ::: "memory"); \
                       __builtin_amdgcn_s_barrier(); \
                       asm volatile("" ::: "memory"); \
                       __builtin_amdgcn_sched_barrier(0); } while (0)
#define WAIT_LGKM() do { asm volatile("s_waitcnt lgkmcnt(0)" ::: "memory"); \
                         __builtin_amdgcn_sched_barrier(0); } while (0)
#define WAIT_VM()   do { asm volatile("s_waitcnt vmcnt(0)" ::: "memory"); \
                         __builtin_amdgcn_sched_barrier(0); } while (0)

#define MFMA16(a, b, c) __builtin_amdgcn_mfma_f32_16x16x32_bf16((a), (b), (c), 0, 0, 0)

__global__ void __launch_bounds__(512, 1)
mdn_kernel(const float* __restrict__ inp, const float* __restrict__ Wk,
           const float* __restrict__ Wr,  const float* __restrict__ bg,
           const float* __restrict__ Wd,  const float* __restrict__ bd,
           float* __restrict__ out, u32* __restrict__ flags, u64* __restrict__ hbuf)
{
    __shared__ __attribute__((aligned(16))) u16  wr_s[64 * HH];   // dead after preamble
    __shared__ __attribute__((aligned(16))) u16  wk_s[64 * 64];   // dead after preamble
    __shared__ __attribute__((aligned(16))) u16  wd_s[16 * HH];   // dead after preamble
    __shared__ __attribute__((aligned(16))) u16  hA[GB * HH];
    __shared__ __attribute__((aligned(16))) u16  hB[GB * HH];
    __shared__ __attribute__((aligned(16))) float gbuf[4 * 16 * 16]; // [q][row][col], shared A/B
    __shared__ __attribute__((aligned(16))) float pbuf[4 * 16 * 16]; // [kw][row][col], shared A/B

    const int tid  = threadIdx.x;
    const int lane = tid & 63;
    const int wave = tid >> 6;
    const int p    = blockIdx.x & 7;     // pair id
    const int s    = blockIdx.x >> 3;    // h-slice 0..31
    const int gA   = 2 * p, gB = 2 * p + 1;
    const int m16  = lane & 15;
    const int kq   = lane >> 4;
    const int brow = m16 & 7;            // batch row (A rows duplicated 8..15)

    // ---------------- preamble: weight staging ----------------
    {
        int n = tid & 63;
        int q = n >> 4, j4 = n & 15;
        int col = q * HH + s * 16 + j4;
        for (int k = tid >> 6; k < HH; k += 8)
            wr_s[n * HH + (k ^ ((n & 7) << 3))] = f2bf(Wr[(size_t)k * 2048 + col]);
        for (int k = tid >> 6; k < 64; k += 8)
            wk_s[n * 64 + (k ^ ((n & 7) << 3))] = f2bf(k < DIN ? Wk[(size_t)k * 2048 + col] : 0.0f);
    }
    {
        int n = tid & 15;
        for (int k = tid >> 4; k < HH; k += 32)
            wd_s[n * HH + (k ^ ((n & 7) << 3))] =
                f2bf(n < ODC ? Wd[(size_t)k * OUTC + s * ODC + n] : 0.0f);
    }
    for (int i = tid; i < GB * HH / 4; i += 512) {   // h(-1) = 0 for both groups
        ((u64*)hA)[i] = 0ull; ((u64*)hB)[i] = 0ull;
    }
    __syncthreads();   // preamble: full sync fine (one-time)

    // ---------------- B-fragments to registers ----------------
    bf16x8 bfr[18];
    if (wave < 4) {
        int n = wave * 16 + m16;
        #pragma unroll
        for (int ks = 0; ks < 16; ++ks) {
            int k0 = 32 * ks + 8 * kq;
            bfr[ks] = *(const bf16x8*)(&wr_s[n * HH + (k0 ^ ((n & 7) << 3))]);
        }
        #pragma unroll
        for (int i = 0; i < 2; ++i) {
            int k0 = 32 * i + 8 * kq;
            bfr[16 + i] = *(const bf16x8*)(&wk_s[n * 64 + (k0 ^ ((n & 7) << 3))]);
        }
    } else {
        int w4 = wave - 4;
        #pragma unroll
        for (int kk = 0; kk < 4; ++kk) {
            int k0 = w4 * 128 + 32 * kk + 8 * kq;
            bfr[kk] = *(const bf16x8*)(&wd_s[m16 * HH + (k0 ^ ((m16 & 7) << 3))]);
        }
    }

    // ---------------- per-thread state ----------------
    float cA = 0.f, cB = 0.f;
    float bi = 0.f, bff = 0.f, bgg = 0.f, boo = 0.f, bdv = 0.f;
    int br = 0, jj = 0, oo = 0;
    if (tid < 128) {
        br = tid >> 4; jj = tid & 15;
        int scol = s * 16 + jj;
        bi  = bg[0 * HH + scol];
        bff = bg[1 * HH + scol];
        bgg = bg[2 * HH + scol];
        boo = bg[3 * HH + scol];
    } else if (tid >= 256 && tid < 384) {
        br = (tid - 256) >> 4; oo = (tid - 256) & 15;
        if (oo < ODC) bdv = bd[s * ODC + oo];
    }

    // x registers: gate lane owns x[batch=brow][kq*8..kq*8+7] + (kq==0) cols 32..34
    float xA[8], xB[8];
    float xeA0 = 0.f, xeA1 = 0.f, xeA2 = 0.f, xeB0 = 0.f, xeB1 = 0.f, xeB2 = 0.f;
    #pragma unroll
    for (int i = 0; i < 8; ++i) { xA[i] = 0.f; xB[i] = 0.f; }
    if (wave < 4) {   // prologue: issue x(0) for both groups
        const float* pa = inp + ((size_t)(gA * GB + brow) * TT + 0) * DIN;
        const float* pb = inp + ((size_t)(gB * GB + brow) * TT + 0) * DIN;
        #pragma unroll
        for (int i = 0; i < 8; ++i) { xA[i] = pa[kq * 8 + i]; xB[i] = pb[kq * 8 + i]; }
        if (kq == 0) { xeA0 = pa[32]; xeA1 = pa[33]; xeA2 = pa[34];
                       xeB0 = pb[32]; xeB1 = pb[33]; xeB2 = pb[34]; }
    }
    __syncthreads();

    for (int t = 0; t <= TT; ++t) {
        // ================= P1: MFMA group A (gates t, out t-1) =================
        if (wave < 4) {
            if (t < TT) {
                bf8u a0, a1;
                a0.u[0] = pk2(xA[0], xA[1]); a0.u[1] = pk2(xA[2], xA[3]);
                a0.u[2] = pk2(xA[4], xA[5]); a0.u[3] = pk2(xA[6], xA[7]);
                a1.u[0] = (kq == 0) ? pk2(xeA0, xeA1) : 0u;
                a1.u[1] = (kq == 0) ? pk2(xeA2, 0.f) : 0u;
                a1.u[2] = 0u; a1.u[3] = 0u;
                f32x4 acc0 = {0,0,0,0}, acc1 = {0,0,0,0};
                acc0 = MFMA16(a0.v, bfr[16], acc0);
                acc1 = MFMA16(a1.v, bfr[17], acc1);
                #pragma unroll
                for (int ks = 0; ks < 16; ks += 2) {
                    int k0 = 32 * ks + 8 * kq;
                    bf16x8 a = *(const bf16x8*)(&hA[brow * HH + (k0 ^ (brow << 3))]);
                    acc0 = MFMA16(a, bfr[ks], acc0);
                    int k1 = 32 * (ks + 1) + 8 * kq;
                    bf16x8 a2 = *(const bf16x8*)(&hA[brow * HH + (k1 ^ (brow << 3))]);
                    acc1 = MFMA16(a2, bfr[ks + 1], acc1);
                }
                #pragma unroll
                for (int j = 0; j < 4; ++j)
                    gbuf[wave * 256 + (kq * 4 + j) * 16 + m16] = acc0[j] + acc1[j];
            }
        } else {
            if (t > 0) {
                int w4 = wave - 4;
                f32x4 acc0 = {0,0,0,0}, acc1 = {0,0,0,0};
                #pragma unroll
                for (int kk = 0; kk < 4; kk += 2) {
                    int k0 = w4 * 128 + 32 * kk + 8 * kq;
                    bf16x8 a = *(const bf16x8*)(&hA[brow * HH + (k0 ^ (brow << 3))]);
                    acc0 = MFMA16(a, bfr[kk], acc0);
                    int k1 = w4 * 128 + 32 * (kk + 1) + 8 * kq;
                    bf16x8 a2 = *(const bf16x8*)(&hA[brow * HH + (k1 ^ (brow << 3))]);
                    acc1 = MFMA16(a2, bfr[kk + 1], acc1);
                }
                #pragma unroll
                for (int j = 0; j < 4; ++j)
                    pbuf[w4 * 256 + (kq * 4 + j) * 16 + m16] = acc0[j] + acc1[j];
            }
        }
        WAIT_LGKM(); BARRIER();

        // ================= P2: scalar A + publish =================
        if (t < TT && tid < 128) {
            float iv = gbuf[0 * 256 + br * 16 + jj] + bi;
            float fv = gbuf[1 * 256 + br * 16 + jj] + bff;
            float gv = gbuf[2 * 256 + br * 16 + jj] + bgg;
            float ov = gbuf[3 * 256 + br * 16 + jj] + boo;
            cA = sigf(fv) * cA + sigf(iv) * tanh_fast(gv);
            float h = sigf(ov) * tanh_fast(cA);
            u32 hb32 = (u32)f2bf(h);
            u32 o1 = (u32)__shfl_xor((int)hb32, 1);
            u32 lo = hb32 | (o1 << 16);
            u32 o2 = (u32)__shfl_xor((int)lo, 2);
            if ((jj & 3) == 0) {
                u64 w = (u64)lo | ((u64)o2 << 32);
                u64* dst = hbuf + (size_t)(t & 1) * (NGRP * HW) + gA * HW
                              + br * 128 + s * 4 + (jj >> 2);
                __hip_atomic_store(dst, w, __ATOMIC_RELAXED, __HIP_MEMORY_SCOPE_AGENT);
            }
        }
        if (t > 0 && tid >= 256 && tid < 384) {
            float v = pbuf[0 * 256 + br * 16 + oo] + pbuf[1 * 256 + br * 16 + oo]
                    + pbuf[2 * 256 + br * 16 + oo] + pbuf[3 * 256 + br * 16 + oo] + bdv;
            if (oo < ODC)
                out[((size_t)(gA * GB + br) * TT + (t - 1)) * OUTC + s * ODC + oo] = v;
        }
        if (t < TT && wave < 2) WAIT_VM();   // drain h stores (publishers only)
        BARRIER();
        if (t < TT && tid == 0)
            __hip_atomic_store(&flags[(gA * 32 + s) * 16], (u32)(t + 1),
                               __ATOMIC_RELAXED, __HIP_MEMORY_SCOPE_AGENT);

        // ================= P3: poll B, load h_B(t-1); issue xA(t+1) =================
        if (t > 0) {
            if (wave == 0) {
                const u32* fp = flags + ((gB * 32) + (lane & 31)) * 16;
                const u32 tgt = (u32)t;
                int spins = 0;
                while (true) {
                    u32 v = __hip_atomic_load(fp, __ATOMIC_RELAXED, __HIP_MEMORY_SCOPE_AGENT);
                    if (__all((int)(v >= tgt))) break;
                    __builtin_amdgcn_s_sleep(1);
                    if (++spins > (1 << 22)) break;       // bounded bail-out: no hangs
                }
            }
            BARRIER();                                     // load-after-flag
            const u64* bp = hbuf + (size_t)((t - 1) & 1) * (NGRP * HW) + gB * HW;
            u64 v0 = __hip_atomic_load(bp + 2 * tid,     __ATOMIC_RELAXED, __HIP_MEMORY_SCOPE_AGENT);
            u64 v1 = __hip_atomic_load(bp + 2 * tid + 1, __ATOMIC_RELAXED, __HIP_MEMORY_SCOPE_AGENT);
            int k8 = lane * 8;
            int sk = k8 ^ ((wave & 7) << 3);
            *(u64*)(&hB[wave * HH + sk])     = v0;
            *(u64*)(&hB[wave * HH + sk + 4]) = v1;
        }
        if (wave < 4 && t + 1 < TT) {                      // x_A(t+1) into regs
            const float* pa = inp + ((size_t)(gA * GB + brow) * TT + (t + 1)) * DIN;
            #pragma unroll
            for (int i = 0; i < 8; ++i) xA[i] = pa[kq * 8 + i];
            if (kq == 0) { xeA0 = pa[32]; xeA1 = pa[33]; xeA2 = pa[34]; }
        }
        WAIT_LGKM(); BARRIER();

        // ================= P4: MFMA group B =================
        if (wave < 4) {
            if (t < TT) {
                bf8u a0, a1;
                a0.u[0] = pk2(xB[0], xB[1]); a0.u[1] = pk2(xB[2], xB[3]);
                a0.u[2] = pk2(xB[4], xB[5]); a0.u[3] = pk2(xB[6], xB[7]);
                a1.u[0] = (kq == 0) ? pk2(xeB0, xeB1) : 0u;
                a1.u[1] = (kq == 0) ? pk2(xeB2, 0.f) : 0u;
                a1.u[2] = 0u; a1.u[3] = 0u;
                f32x4 acc0 = {0,0,0,0}, acc1 = {0,0,0,0};
                acc0 = MFMA16(a0.v, bfr[16], acc0);
                acc1 = MFMA16(a1.v, bfr[17], acc1);
                #pragma unroll
                for (int ks = 0; ks < 16; ks += 2) {
                    int k0 = 32 * ks + 8 * kq;
                    bf16x8 a = *(const bf16x8*)(&hB[brow * HH + (k0 ^ (brow << 3))]);
                    acc0 = MFMA16(a, bfr[ks], acc0);
                    int k1 = 32 * (ks + 1) + 8 * kq;
                    bf16x8 a2 = *(const bf16x8*)(&hB[brow * HH + (k1 ^ (brow << 3))]);
                    acc1 = MFMA16(a2, bfr[ks + 1], acc1);
                }
                #pragma unroll
                for (int j = 0; j < 4; ++j)
                    gbuf[wave * 256 + (kq * 4 + j) * 16 + m16] = acc0[j] + acc1[j];
            }
        } else {
            if (t > 0) {
                int w4 = wave - 4;
                f32x4 acc0 = {0,0,0,0}, acc1 = {0,0,0,0};
                #pragma unroll
                for (int kk = 0; kk < 4; kk += 2) {
                    int k0 = w4 * 128 + 32 * kk + 8 * kq;
                    bf16x8 a = *(const bf16x8*)(&hB[brow * HH + (k0 ^ (brow << 3))]);
                    acc0 = MFMA16(a, bfr[kk], acc0);
                    int k1 = w4 * 128 + 32 * (kk + 1) + 8 * kq;
                    bf16x8 a2 = *(const bf16x8*)(&hB[brow * HH + (k1 ^ (brow << 3))]);
                    acc1 = MFMA16(a2, bfr[kk + 1], acc1);
                }
                #pragma unroll
                for (int j = 0; j < 4; ++j)
                    pbuf[w4 * 256 + (kq * 4 + j) * 16 + m16] = acc0[j] + acc1[j];
            }
        }
        WAIT_LGKM(); BARRIER();

        // ================= P5: scalar B + publish =================
        if (t < TT && tid < 128) {
            float iv = gbuf[0 * 256 + br * 16 + jj] + bi;
            float fv = gbuf[1 * 256 + br * 16 + jj] + bff;
            float gv = gbuf[2 * 256 + br * 16 + jj] + bgg;
            float ov = gbuf[3 * 256 + br * 16 + jj] + boo;
            cB = sigf(fv) * cB + sigf(iv) * tanh_fast(gv);
            float h = sigf(ov) * tanh_fast(cB);
            u32 hb32 = (u32)f2bf(h);
            u32 o1 = (u32)__shfl_xor((int)hb32, 1);
            u32 lo = hb32 | (o1 << 16);
            u32 o2 = (u32)__shfl_xor((int)lo, 2);
            if ((jj & 3) == 0) {
                u64 w = (u64)lo | ((u64)o2 << 32);
                u64* dst = hbuf + (size_t)(t & 1) * (NGRP * HW) + gB * HW
                              + br * 128 + s * 4 + (jj >> 2);
                __hip_atomic_store(dst, w, __ATOMIC_RELAXED, __HIP_MEMORY_SCOPE_AGENT);
            }
        }
        if (t > 0 && tid >= 256 && tid < 384) {
            float v = pbuf[0 * 256 + br * 16 + oo] + pbuf[1 * 256 + br * 16 + oo]
                    + pbuf[2 * 256 + br * 16 + oo] + pbuf[3 * 256 + br * 16 + oo] + bdv;
            if (oo < ODC)
                out[((size_t)(gB * GB + br) * TT + (t - 1)) * OUTC + s * ODC + oo] = v;
        }
        if (t < TT && wave < 2) WAIT_VM();
        BARRIER();
        if (t < TT && tid == 0)
            __hip_atomic_store(&flags[(gB * 32 + s) * 16], (u32)(t + 1),
                               __ATOMIC_RELAXED, __HIP_MEMORY_SCOPE_AGENT);

        // ================= P6: poll A, load h_A(t); issue xB(t+1) =================
        if (t < TT) {
            if (wave == 0) {
                const u32* fp = flags + ((gA * 32) + (lane & 31)) * 16;
                const u32 tgt = (u32)(t + 1);
                int spins = 0;
                while (true) {
                    u32 v = __hip_atomic_load(fp, __ATOMIC_RELAXED, __HIP_MEMORY_SCOPE_AGENT);
                    if (__all((int)(v >= tgt))) break;
                    __builtin_amdgcn_s_sleep(1);
                    if (++spins > (1 << 22)) break;
                }
            }
            BARRIER();
            const u64* bp = hbuf + (size_t)(t & 1) * (NGRP * HW) + gA * HW;
            u64 v0 = __hip_atomic_load(bp + 2 * tid,     __ATOMIC_RELAXED, __HIP_MEMORY_SCOPE_AGENT);
            u64 v1 = __hip_atomic_load(bp + 2 * tid + 1, __ATOMIC_RELAXED, __HIP_MEMORY_SCOPE_AGENT);
            int k8 = lane * 8;
            int sk = k8 ^ ((wave & 7) << 3);
            *(u64*)(&hA[wave * HH + sk])     = v0;
            *(u64*)(&hA[wave * HH + sk + 4]) = v1;
            if (wave < 4 && t + 1 < TT) {                  // x_B(t+1) into regs
                const float* pb = inp + ((size_t)(gB * GB + brow) * TT + (t + 1)) * DIN;
                #pragma unroll
                for (int i = 0; i < 8; ++i) xB[i] = pb[kq * 8 + i];
                if (kq == 0) { xeB0 = pb[32]; xeB1 = pb[33]; xeB2 = pb[34]; }
            }
            WAIT_LGKM(); BARRIER();
        }
    }
}

extern "C" void kernel_launch(void* const* d_in, const int* in_sizes, int n_in,
                              void* d_out, int out_size, void* d_ws, size_t ws_size,
                              hipStream_t stream) {
    const float* inp = (const float*)d_in[0];
    const float* Wk  = (const float*)d_in[1];
    const float* Wr  = (const float*)d_in[2];
    const float* bg  = (const float*)d_in[3];
    const float* Wd  = (const float*)d_in[4];
    const float* bd  = (const float*)d_in[5];
    float* out = (float*)d_out;

    // ws: [0, 32768): flags, 16 groups x 32 slices x 16 u32 (64B apart, zeroed)
    //     [32768, 32768+262144): h double buffers, 2 x 16 x 1024 u64
    char* ws = (char*)d_ws;
    u32* flags = (u32*)ws;
    u64* hbuf  = (u64*)(ws + 32768);
    hipMemsetAsync(d_ws, 0, 32768, stream);   // flags only (hbuf is flag-gated)

    hipLaunchKernelGGL(mdn_kernel, dim3(256), dim3(512), 0, stream,
                       inp, Wk, Wr, bg, Wd, bd, out, flags, hbuf);
}

// Round 10
// 2818.563 us; speedup vs baseline: 3.2334x; 1.6174x over previous
//
#include <hip/hip_runtime.h>

// MDN-RNN persistent kernel for MI355X (gfx950).
// R10 = R4's proven exchange protocol + R9's structural cleanups, single group.
// B=128, T=1000, D_IN=35, H=512, OUT=480.
// 8 batch-groups (16 batches) x 32 h-slice WGs = 256 WGs, 1/CU.
// Exchange per step (R4 verbatim): h u64 relaxed-agent stores -> publisher-wave
// vmcnt(0) -> barrier -> tid0 flag -> wave0 polls 32 flags (s_sleep) -> barrier
// -> all-thread bulk load (4 u64/thread) -> swizzled ds_write -> barrier.
// Cleanups (R9-validated): raw s_barrier + typed waits (x loads ride across
// barriers), x per-lane registers (no in_s), reg-resident B-frags (gate waves
// 16 ds_read_b128/step), publisher-only drains.
// Lessons: R8 never trust placement; R7 minimal pollers; R5/R6 no traffic
// amplification; R1/R3 no cache-wide maintenance ops.

#define NGRP   8
#define NSLICE 32
#define GB     16
#define HH     512
#define TT     1000
#define DIN    35
#define OUTC   480
#define ODC    15
#define HWORDS 2048      // u64 words per group h snapshot (16*512/4)

typedef __bf16 bf16x8 __attribute__((ext_vector_type(8)));
typedef float  f32x4  __attribute__((ext_vector_type(4)));
typedef unsigned short u16;
typedef unsigned int   u32;
typedef unsigned long long u64;

__device__ __forceinline__ u16 f2bf(float x) {
    u32 u = __float_as_uint(x);
    u += 0x7FFFu + ((u >> 16) & 1u);
    return (u16)(u >> 16);
}
__device__ __forceinline__ u32 pk2(float a, float b) {
    return (u32)f2bf(a) | ((u32)f2bf(b) << 16);
}
__device__ __forceinline__ float sigf(float x) { return 1.0f / (1.0f + __expf(-x)); }
__device__ __forceinline__ float tanh_fast(float x) {
    float ax = fabsf(x);
    float e = __expf(-2.0f * ax);
    return copysignf((1.0f - e) / (1.0f + e), x);
}

union bf8u { u32 u[4]; bf16x8 v; };

// raw barrier with compiler-level memory fence + sched pin (guide rule #18)
#define BARRIER() do { asm volatile("" ::: "memory"); \
                       __builtin_amdgcn_s_barrier(); \
                       asm volatile("" ::: "memory"); \
                       __builtin_amdgcn_sched_barrier(0); } while (0)
#define WAIT_LGKM() do { asm volatile("s_waitcnt lgkmcnt(0)" ::: "memory"); \
                         __builtin_amdgcn_sched_barrier(0); } while (0)
#define WAIT_VM()   do { asm volatile("s_waitcnt vmcnt(0)" ::: "memory"); \
                         __builtin_amdgcn_sched_barrier(0); } while (0)

#define MFMA16(a, b, c) __builtin_amdgcn_mfma_f32_16x16x32_bf16((a), (b), (c), 0, 0, 0)

__global__ void __launch_bounds__(512, 1)
mdn_kernel(const float* __restrict__ inp, const float* __restrict__ Wk,
           const float* __restrict__ Wr,  const float* __restrict__ bg,
           const float* __restrict__ Wd,  const float* __restrict__ bd,
           float* __restrict__ out, u32* __restrict__ flags, u64* __restrict__ hbuf)
{
    __shared__ __attribute__((aligned(16))) u16  wr_s[64 * HH];   // dead after preamble
    __shared__ __attribute__((aligned(16))) u16  wk_s[64 * 64];   // dead after preamble
    __shared__ __attribute__((aligned(16))) u16  wd_s[16 * HH];   // dead after preamble
    __shared__ __attribute__((aligned(16))) u16  h_s [GB * HH];
    __shared__ __attribute__((aligned(16))) float gbuf[4 * 16 * 16]; // [q][batch][col]
    __shared__ __attribute__((aligned(16))) float pbuf[4 * 16 * 16]; // [kw][batch][col]

    const int tid  = threadIdx.x;
    const int lane = tid & 63;
    const int wave = tid >> 6;
    const int g    = blockIdx.x & 7;    // batch group (XCD-affine under round-robin)
    const int s    = blockIdx.x >> 3;   // h-slice 0..31
    const int m16  = lane & 15;
    const int kq   = lane >> 4;

    // ---------------- preamble: weight staging + h_s zero ----------------
    {
        int n = tid & 63;
        int q = n >> 4, j4 = n & 15;
        int col = q * HH + s * 16 + j4;
        for (int k = tid >> 6; k < HH; k += 8)
            wr_s[n * HH + (k ^ ((n & 7) << 3))] = f2bf(Wr[(size_t)k * 2048 + col]);
        for (int k = tid >> 6; k < 64; k += 8)
            wk_s[n * 64 + (k ^ ((n & 7) << 3))] = f2bf(k < DIN ? Wk[(size_t)k * 2048 + col] : 0.0f);
    }
    {
        int n = tid & 15;
        for (int k = tid >> 4; k < HH; k += 32)
            wd_s[n * HH + (k ^ ((n & 7) << 3))] =
                f2bf(n < ODC ? Wd[(size_t)k * OUTC + s * ODC + n] : 0.0f);
    }
    for (int i = tid; i < GB * HH / 4; i += 512) ((u64*)h_s)[i] = 0ull;  // h_{-1}=0
    __syncthreads();   // one-time full sync

    // ---------------- B-fragments to registers ----------------
    bf16x8 bfr[18];
    if (wave < 4) {
        int n = wave * 16 + m16;
        #pragma unroll
        for (int ks = 0; ks < 16; ++ks) {
            int k0 = 32 * ks + 8 * kq;
            bfr[ks] = *(const bf16x8*)(&wr_s[n * HH + (k0 ^ ((n & 7) << 3))]);
        }
        #pragma unroll
        for (int i = 0; i < 2; ++i) {
            int k0 = 32 * i + 8 * kq;
            bfr[16 + i] = *(const bf16x8*)(&wk_s[n * 64 + (k0 ^ ((n & 7) << 3))]);
        }
    } else {
        int w4 = wave - 4;
        #pragma unroll
        for (int kk = 0; kk < 4; ++kk) {
            int k0 = w4 * 128 + 32 * kk + 8 * kq;
            bfr[kk] = *(const bf16x8*)(&wd_s[m16 * HH + (k0 ^ ((m16 & 7) << 3))]);
        }
    }

    // ---------------- per-thread state ----------------
    float c_reg = 0.f;
    float bi = 0.f, bff = 0.f, bgg = 0.f, boo = 0.f, bdv = 0.f;
    int br = 0, jj = 0, oo = 0;
    if (tid < 256) {
        br = tid >> 4; jj = tid & 15;
        int scol = s * 16 + jj;
        bi  = bg[0 * HH + scol];
        bff = bg[1 * HH + scol];
        bgg = bg[2 * HH + scol];
        boo = bg[3 * HH + scol];
    } else {
        br = (tid - 256) >> 4; oo = (tid - 256) & 15;
        if (oo < ODC) bdv = bd[s * ODC + oo];
    }

    // x registers: gate lane owns x[batch=m16][kq*8..kq*8+7] (+ cols 32..34, kq==0)
    float xr[8];
    float xe0 = 0.f, xe1 = 0.f, xe2 = 0.f;
    #pragma unroll
    for (int i = 0; i < 8; ++i) xr[i] = 0.f;
    if (wave < 4) {   // prologue: x(0)
        const float* ip = inp + ((size_t)(g * GB + m16) * TT + 0) * DIN;
        #pragma unroll
        for (int i = 0; i < 8; ++i) xr[i] = ip[kq * 8 + i];
        if (kq == 0) { xe0 = ip[32]; xe1 = ip[33]; xe2 = ip[34]; }
    }
    __syncthreads();

    // bulk-load geometry (R4-proven): thread owns 16 h values (4 u64)
    const int pb = tid >> 5;      // batch row 0..15
    const int pk = tid & 31;      // k chunks pk*8 + i*256, i=0,1

    for (int t = 0; t <= TT; ++t) {
        // invariant: h_s = h_{t-1}; xr = x_t
        // ================= P1: MFMA phase =================
        if (wave < 4) {
            if (t < TT) {
                bf8u a0, a1;
                a0.u[0] = pk2(xr[0], xr[1]); a0.u[1] = pk2(xr[2], xr[3]);
                a0.u[2] = pk2(xr[4], xr[5]); a0.u[3] = pk2(xr[6], xr[7]);
                a1.u[0] = (kq == 0) ? pk2(xe0, xe1) : 0u;
                a1.u[1] = (kq == 0) ? pk2(xe2, 0.f) : 0u;
                a1.u[2] = 0u; a1.u[3] = 0u;
                f32x4 acc0 = {0,0,0,0}, acc1 = {0,0,0,0};
                acc0 = MFMA16(a0.v, bfr[16], acc0);      // xz K-tile 0..31
                acc1 = MFMA16(a1.v, bfr[17], acc1);      // xz K-tile 32..63 (pad 0)
                #pragma unroll
                for (int ks = 0; ks < 16; ks += 2) {     // h @ Wr, 2-way ILP
                    int k0 = 32 * ks + 8 * kq;
                    bf16x8 a = *(const bf16x8*)(&h_s[m16 * HH + (k0 ^ ((m16 & 7) << 3))]);
                    acc0 = MFMA16(a, bfr[ks], acc0);
                    int k1 = 32 * (ks + 1) + 8 * kq;
                    bf16x8 a2 = *(const bf16x8*)(&h_s[m16 * HH + (k1 ^ ((m16 & 7) << 3))]);
                    acc1 = MFMA16(a2, bfr[ks + 1], acc1);
                }
                #pragma unroll
                for (int j = 0; j < 4; ++j)
                    gbuf[wave * 256 + (kq * 4 + j) * 16 + m16] = acc0[j] + acc1[j];
            }
        } else {
            if (t > 0) {    // out row t-1, k-split across waves 4..7
                int w4 = wave - 4;
                f32x4 acc0 = {0,0,0,0}, acc1 = {0,0,0,0};
                #pragma unroll
                for (int kk = 0; kk < 4; kk += 2) {
                    int k0 = w4 * 128 + 32 * kk + 8 * kq;
                    bf16x8 a = *(const bf16x8*)(&h_s[m16 * HH + (k0 ^ ((m16 & 7) << 3))]);
                    acc0 = MFMA16(a, bfr[kk], acc0);
                    int k1 = w4 * 128 + 32 * (kk + 1) + 8 * kq;
                    bf16x8 a2 = *(const bf16x8*)(&h_s[m16 * HH + (k1 ^ ((m16 & 7) << 3))]);
                    acc1 = MFMA16(a2, bfr[kk + 1], acc1);
                }
                #pragma unroll
                for (int j = 0; j < 4; ++j)
                    pbuf[w4 * 256 + (kq * 4 + j) * 16 + m16] = acc0[j] + acc1[j];
            }
        }
        WAIT_LGKM(); BARRIER();

        // ================= P2: scalar phase =================
        if (tid < 256) {
            if (t < TT) {
                float iv = gbuf[0 * 256 + br * 16 + jj] + bi;
                float fv = gbuf[1 * 256 + br * 16 + jj] + bff;
                float gv = gbuf[2 * 256 + br * 16 + jj] + bgg;
                float ov = gbuf[3 * 256 + br * 16 + jj] + boo;
                c_reg = sigf(fv) * c_reg + sigf(iv) * tanh_fast(gv);
                float h = sigf(ov) * tanh_fast(c_reg);
                u32 hb32 = (u32)f2bf(h);
                u32 o1 = (u32)__shfl_xor((int)hb32, 1);
                u32 lo = hb32 | (o1 << 16);                // valid on even jj
                u32 o2 = (u32)__shfl_xor((int)lo, 2);      // jj%4==0 gets (jj+2,jj+3)
                if ((jj & 3) == 0) {
                    u64 w = (u64)lo | ((u64)o2 << 32);
                    u64* dst = hbuf + (size_t)(t & 1) * (NGRP * HWORDS) + g * HWORDS
                                  + br * 128 + s * 4 + (jj >> 2);
                    __hip_atomic_store(dst, w, __ATOMIC_RELAXED, __HIP_MEMORY_SCOPE_AGENT);
                }
            }
        } else {
            if (t > 0) {    // reduce out partials + store f32
                float v = pbuf[0 * 256 + br * 16 + oo] + pbuf[1 * 256 + br * 16 + oo]
                        + pbuf[2 * 256 + br * 16 + oo] + pbuf[3 * 256 + br * 16 + oo] + bdv;
                if (oo < ODC)
                    out[((size_t)(g * GB + br) * TT + (t - 1)) * OUTC + s * ODC + oo] = v;
            }
        }

        // ================= P3: exchange =================
        if (t < TT) {
            if (wave < 4) WAIT_VM();           // publishers drain own h stores
            BARRIER();                         // all h at coherence point
            if (tid == 0)
                __hip_atomic_store(&flags[(g * NSLICE + s) * 16], (u32)(t + 1),
                                   __ATOMIC_RELAXED, __HIP_MEMORY_SCOPE_AGENT);
            // x(t+1) prefetch into registers (rides across barriers, ~1.5us to land)
            if (wave < 4 && t + 1 < TT) {
                const float* ip = inp + ((size_t)(g * GB + m16) * TT + (t + 1)) * DIN;
                #pragma unroll
                for (int i = 0; i < 8; ++i) xr[i] = ip[kq * 8 + i];
                if (kq == 0) { xe0 = ip[32]; xe1 = ip[33]; xe2 = ip[34]; }
            }
            // detect: wave0 polls 32 flags (R4-proven)
            if (wave == 0) {
                const u32* fp = flags + (g * NSLICE + (lane & 31)) * 16;
                const u32 tgt = (u32)(t + 1);
                int spins = 0;
                while (true) {
                    u32 v = __hip_atomic_load(fp, __ATOMIC_RELAXED, __HIP_MEMORY_SCOPE_AGENT);
                    if (__all((int)(v >= tgt))) break;
                    __builtin_amdgcn_s_sleep(1);
                    if (++spins > (1 << 20)) break;        // bounded bail-out: no hangs
                }
            }
            BARRIER();
            // bulk load h_t (4 u64/thread, R4 mapping) + swizzled ds_write
            {
                const u64* bp = hbuf + (size_t)(t & 1) * (NGRP * HWORDS) + g * HWORDS;
                #pragma unroll
                for (int i = 0; i < 2; ++i) {
                    int widx = pb * 128 + pk * 2 + i * 64;
                    u64 vlo = __hip_atomic_load(bp + widx,     __ATOMIC_RELAXED, __HIP_MEMORY_SCOPE_AGENT);
                    u64 vhi = __hip_atomic_load(bp + widx + 1, __ATOMIC_RELAXED, __HIP_MEMORY_SCOPE_AGENT);
                    int k  = pk * 8 + i * 256;
                    int sk = k ^ ((pb & 7) << 3);          // XOR moves 8-blocks whole
                    *(u64*)(&h_s[pb * HH + sk])     = vlo;
                    *(u64*)(&h_s[pb * HH + sk + 4]) = vhi;
                }
            }
            WAIT_LGKM(); BARRIER();
        }
    }
}

extern "C" void kernel_launch(void* const* d_in, const int* in_sizes, int n_in,
                              void* d_out, int out_size, void* d_ws, size_t ws_size,
                              hipStream_t stream) {
    const float* inp = (const float*)d_in[0];
    const float* Wk  = (const float*)d_in[1];
    const float* Wr  = (const float*)d_in[2];
    const float* bg  = (const float*)d_in[3];
    const float* Wd  = (const float*)d_in[4];
    const float* bd  = (const float*)d_in[5];
    float* out = (float*)d_out;

    // ws: [0,16384): flags, 8 groups x 32 slices x 16 u32 (64B apart, zeroed)
    //     [16384, 16384+262144): h double buffers, 2 x 8 x 2048 u64 (flag-gated)
    char* ws = (char*)d_ws;
    u32* flags = (u32*)ws;
    u64* hbuf  = (u64*)(ws + 16384);
    hipMemsetAsync(d_ws, 0, 16384, stream);

    hipLaunchKernelGGL(mdn_kernel, dim3(NGRP * NSLICE), dim3(512), 0, stream,
                       inp, Wk, Wr, bg, Wd, bd, out, flags, hbuf);
}